// Round 7
// baseline (230.699 us; speedup 1.0000x reference)
//
#include <hip/hip_runtime.h>

// out0 = cumsum(z, axis=0), z fp32 [8192, 64, 128] -> 8192 rows x 8192 contiguous cols.
// out1 = previous_loss (1 float) at d_out[8192*8192].
//
// Fused single-kernel scan, z read twice but the second read is MALL-warm:
//   A: per-chunk aggregate (no slice stores), publish agg + release flag.
//   B: wave-parallel lookback -- chain depth 64 == one 64-lane poll window
//      (all 512 blocks co-resident: no dispatch-order assumption, no deadlock).
//   C: re-read z (read <=~40us ago -> Infinity Cache hits), seed with prefix,
//      nontemporal-store out (no MALL allocation -> doesn't evict z).
// Summation grouping identical to round-3 kernel (absmax 1.0).

typedef float f4 __attribute__((ext_vector_type(4)));

constexpr int NROWS = 8192;
constexpr int NCOLS = 8192;
constexpr int NCOL4 = NCOLS / 4;     // 2048 float4 per row
constexpr int TPB   = 256;

constexpr int KCH   = 64;            // chunks == chain depth (<=64: single window)
constexpr int R     = NROWS / KCH;   // 128 rows per chunk
constexpr int NTILE = NCOL4 / TPB;   // 8 column tiles
constexpr int GRID  = KCH * NTILE;   // 512 blocks, all co-resident on 256 CUs

__global__ __launch_bounds__(TPB) void k_onepass(
    const f4* __restrict__ z, f4* __restrict__ out,
    f4* __restrict__ agg, unsigned int* __restrict__ flags,
    const float* __restrict__ prev, float* __restrict__ out_tail)
{
    const int bid   = blockIdx.x;
    const int chunk = bid >> 3;          // chunk-major dispatch
    const int tile  = bid & (NTILE - 1);
    const int tid   = threadIdx.x;
    const int c4    = tile * TPB + tid;

    if (bid == 0 && tid == 0) out_tail[0] = prev[0];

    const f4* p = z + (size_t)chunk * R * NCOL4 + c4;

    // Phase A: chunk aggregate (normal loads -> lines cached for phase C).
    f4 a = (f4)0.f;
    #pragma unroll 16
    for (int r = 0; r < R; ++r) a += p[(size_t)r * NCOL4];

    const int slot = tile * KCH + chunk;          // per-chain contiguous
    agg[(size_t)slot * TPB + tid] = a;
    __threadfence();
    __syncthreads();
    if (tid == 0)
        __hip_atomic_store(&flags[slot], 1u, __ATOMIC_RELEASE,
                           __HIP_MEMORY_SCOPE_AGENT);

    // Phase B: wave 0 polls ALL predecessor flags in parallel (chain depth
    // <= 63 fits one 64-lane window), then all threads sum pred aggregates.
    f4 prefix = (f4)0.f;
    if (chunk > 0) {
        if (tid < chunk) {   // lanes of wave 0 (chunk <= 63 < 64)
            const int fs = tile * KCH + tid;
            while (__hip_atomic_load(&flags[fs], __ATOMIC_RELAXED,
                                     __HIP_MEMORY_SCOPE_AGENT) == 0u)
                __builtin_amdgcn_s_sleep(8);
        }
        __syncthreads();
        __builtin_amdgcn_fence(__ATOMIC_ACQUIRE, "agent");
        const f4* ap = agg + (size_t)tile * KCH * TPB + tid;
        #pragma unroll 4
        for (int cp = 0; cp < chunk; ++cp)
            prefix += ap[(size_t)cp * TPB];       // coalesced, L2/MALL-resident
    }

    // Phase C: re-read z (MALL-warm), running cumsum, nontemporal out stores.
    f4* q = out + (size_t)chunk * R * NCOL4 + c4;
    f4 s = prefix;
    #pragma unroll 8
    for (int r = 0; r < R; ++r) {
        s += p[(size_t)r * NCOL4];
        __builtin_nontemporal_store(s, &q[(size_t)r * NCOL4]);
    }
}

// ---------- fallback 3-pass (known-good, 136 us) ----------
constexpr int FKCH = 128;
constexpr int FRR  = NROWS / FKCH;
constexpr int FCT  = NCOL4 / TPB;

__global__ __launch_bounds__(TPB) void k_partial(const f4* __restrict__ z,
                                                 f4* __restrict__ part) {
    const int tile  = blockIdx.x & (FCT - 1);
    const int chunk = blockIdx.x >> 3;
    const int c4    = tile * TPB + threadIdx.x;
    const f4* p = z + (size_t)chunk * FRR * NCOL4 + c4;
    f4 a = (f4)0.f;
    #pragma unroll 8
    for (int r = 0; r < FRR; ++r) a += p[(size_t)r * NCOL4];
    part[(size_t)chunk * NCOL4 + c4] = a;
}

__global__ __launch_bounds__(TPB) void k_scan(float* __restrict__ part,
                                              const float* __restrict__ prev,
                                              float* __restrict__ out_tail) {
    const int c = blockIdx.x * TPB + threadIdx.x;
    float run = 0.f;
    #pragma unroll 16
    for (int k = 0; k < FKCH; ++k) {
        const size_t i = (size_t)k * NCOLS + c;
        float v = part[i];
        part[i] = run;
        run += v;
    }
    if (blockIdx.x == 0 && threadIdx.x == 0) out_tail[0] = prev[0];
}

__global__ __launch_bounds__(TPB) void k_apply(const f4* __restrict__ z,
                                               const f4* __restrict__ part,
                                               f4* __restrict__ out) {
    const int tile  = blockIdx.x & (FCT - 1);
    const int chunk = FKCH - 1 - (blockIdx.x >> 3);
    const int c4    = tile * TPB + threadIdx.x;
    f4 a = part[(size_t)chunk * NCOL4 + c4];
    const f4* p = z   + (size_t)chunk * FRR * NCOL4 + c4;
    f4*       q = out + (size_t)chunk * FRR * NCOL4 + c4;
    #pragma unroll 4
    for (int r = 0; r < FRR; ++r) {
        a += p[(size_t)r * NCOL4];
        __builtin_nontemporal_store(a, &q[(size_t)r * NCOL4]);
    }
}

extern "C" void kernel_launch(void* const* d_in, const int* in_sizes, int n_in,
                              void* d_out, int out_size, void* d_ws, size_t ws_size,
                              hipStream_t stream) {
    const f4*    z    = (const f4*)d_in[0];
    const float* prev = (const float*)d_in[1];
    float*       out  = (float*)d_out;
    float*       tail = out + (size_t)NROWS * NCOLS;

    const size_t agg_bytes  = (size_t)GRID * TPB * sizeof(f4);  // 2 MiB
    const size_t flag_bytes = (size_t)GRID * sizeof(unsigned int);

    if (ws_size >= agg_bytes + flag_bytes) {
        f4* agg = (f4*)d_ws;
        unsigned int* flags = (unsigned int*)((char*)d_ws + agg_bytes);
        hipMemsetAsync(flags, 0, flag_bytes, stream);
        k_onepass<<<GRID, TPB, 0, stream>>>(z, (f4*)out, agg, flags, prev, tail);
    } else {
        float* part = (float*)d_ws;
        k_partial<<<FKCH * FCT, TPB, 0, stream>>>(z, (f4*)part);
        k_scan<<<NCOLS / TPB, TPB, 0, stream>>>(part, prev, tail);
        k_apply<<<FKCH * FCT, TPB, 0, stream>>>(z, (const f4*)part, (f4*)out);
    }
}